// Round 11
// baseline (106.008 us; speedup 1.0000x reference)
//
#include <hip/hip_runtime.h>
#include <hip/hip_bf16.h>

// Problem: B=2, L=64, F=128. Output (B, L(a), L(t), L(s), 2F) f32 = 512 MiB.
// out[b,a,t,s,0:128]   = mask * (P[b,s]-P[b,a])/(s-a)   [sign cancels]
// out[b,a,t,s,128:256] = mask * (P[b,s]-P[b,t])/(s-t)
// mask = (a!=t)&(a!=s)&(t!=s); P[k] = sum x[0..k-1].
// Pure write-BW bound: 512 MiB out, 64 KiB in.
//
// R11 A/B vs R10 (stream length): each wave writes TWO ADJACENT whole
// t-planes (s = 0..63 each) -> one unbroken 128 KB contiguous stream per
// wave, 8x longer than R10's 16 KB quadrant sweeps. P[s] comes from LDS
// per-step (register-vs-load proven null in R3/R4). Everything else
// (fused LDS prologue, t-group 8, plain stores, uniform mask) unchanged.

#define B_ 2
#define L_ 64
#define F_ 128

typedef float f32x4 __attribute__((ext_vector_type(4)));

// One block per (b, a, t-group of 8): 1024 blocks, 512 KiB contiguous each.
__global__ __launch_bounds__(256) void writer_kernel(f32x4* __restrict__ out,
                                                     const float* __restrict__ x) {
    const int bid = blockIdx.x;          // (b*64 + a)*8 + tg
    const int tg = bid & 7;
    const int a  = (bid >> 3) & 63;
    const int b  = bid >> 9;
    const int t0 = tg << 3;
    const int tid = threadIdx.x;

    __shared__ float Ps[L_][F_];         // 32 KB: P[0..63]

    if (tid < F_) {                      // waves 0-1: one cumsum column each
        const float* xb = x + (b << 13) + tid;   // b*L*F + column
        float run = 0.0f;
#pragma unroll 8
        for (int r = 0; r < L_; ++r) {
            Ps[r][tid] = run;            // Ps[r] = P[r] = sum x[0..r-1]
            run += xb[r << 7];
        }
    }
    __syncthreads();

    const int f4 = tid & 63;             // float4 index within the 256-float row
    const int w  = tid >> 6;             // wave id 0..3
    const bool lower = (f4 < 32);        // lanes 0..31: i=a half; 32..63: i=t half
    const float* base = &Ps[0][0] + ((f4 & 31) << 2);

    const f32x4 z = {0.f, 0.f, 0.f, 0.f};
    const f32x4 pa = *reinterpret_cast<const f32x4*>(base + (a << 7));
    const float fa = (float)a;

    // Wave w owns adjacent planes t = t0+2w and t0+2w+1 -> its stores form
    // one contiguous 128 KB stream (64 KB per plane, planes adjacent).
#pragma unroll
    for (int half = 0; half < 2; ++half) {
        const int t = t0 + (w << 1) + half;          // wave-uniform
        const bool plane_zero = (a == t);            // wave-uniform
        const f32x4 ptv = *reinterpret_cast<const f32x4*>(base + (t << 7));
        const f32x4 pi = lower ? pa : ptv;           // per-lane select
        const float fi = lower ? fa : (float)t;
        // out index (f32x4 units): (((b*64+a)*64 + t)*64 + s)*64 + f4
        f32x4* ot = out + ((size_t)(((b << 6) + a) << 6) + t) * 4096 + f4;

#pragma unroll 8
        for (int s = 0; s < L_; ++s) {               // 64 KB contiguous sweep
            f32x4 v;
            if (plane_zero || s == a || s == t) {    // wave-uniform
                v = z;
            } else {                                  // here s != i for all lanes
                const f32x4 ps = *reinterpret_cast<const f32x4*>(base + (s << 7));
                const float r = __builtin_amdgcn_rcpf((float)s - fi);
                v = (ps - pi) * r;
            }
            ot[s * 64] = v;
        }
    }
}

extern "C" void kernel_launch(void* const* d_in, const int* in_sizes, int n_in,
                              void* d_out, int out_size, void* d_ws, size_t ws_size,
                              hipStream_t stream) {
    const float* x = (const float*)d_in[0];
    f32x4* out = (f32x4*)d_out;

    writer_kernel<<<B_ * L_ * (L_ / 8), 256, 0, stream>>>(out, x);
}

// Round 12
// 99.054 us; speedup vs baseline: 1.0702x; 1.0702x over previous
//
#include <hip/hip_runtime.h>
#include <hip/hip_bf16.h>

// Problem: B=2, L=64, F=128. Output (B, L(a), L(t), L(s), 2F) f32 = 512 MiB.
// out[b,a,t,s,0:128]   = mask * (P[b,s]-P[b,a])/(s-a)   [sign cancels]
// out[b,a,t,s,128:256] = mask * (P[b,s]-P[b,t])/(s-t)
// mask = (a!=t)&(a!=s)&(t!=s); P[k] = sum x[0..k-1], P[64] never used.
// Pure write-BW bound: 512 MiB out, 64 KiB in.
//
// R12: revert to R10 exactly (best measured: 99.25 us). R11's longer
// per-wave streams regressed (106 us) -> store-pattern space exhausted.
// R10 = single fused kernel: waves 0-1 rebuild P into 32KB LDS (one cumsum
// column per thread), barrier, then t-group-8 store structure with
// per-wave contiguous 16KB sweeps, register p[16], plain stores,
// wave-uniform mask branches.

#define B_ 2
#define L_ 64
#define F_ 128

typedef float f32x4 __attribute__((ext_vector_type(4)));

// One block per (b, a, t-group of 8): 1024 blocks, 512 KiB contiguous each.
__global__ __launch_bounds__(256) void writer_kernel(f32x4* __restrict__ out,
                                                     const float* __restrict__ x) {
    const int bid = blockIdx.x;          // (b*64 + a)*8 + tg
    const int tg = bid & 7;
    const int a  = (bid >> 3) & 63;
    const int b  = bid >> 9;
    const int t0 = tg << 3;
    const int tid = threadIdx.x;

    __shared__ float Ps[L_][F_];         // 32 KB: P[0..63]

    if (tid < F_) {                      // waves 0-1: one cumsum column each
        const float* xb = x + (b << 13) + tid;   // b*L*F + column
        float run = 0.0f;
#pragma unroll 8
        for (int r = 0; r < L_; ++r) {
            Ps[r][tid] = run;            // Ps[r] = P[r] = sum x[0..r-1]
            run += xb[r << 7];
        }
    }
    __syncthreads();

    const int f4 = tid & 63;             // float4 index within the 256-float row
    const int s0 = (tid >> 6) << 4;      // this wave's first s

    // out index (f32x4 units): (((b*64+a)*64 + t)*64 + s)*64 + f4
    f32x4* o = out + ((size_t)(((b << 6) + a) << 6) + t0) * 4096 + s0 * 64 + f4;

    const f32x4 z = {0.f, 0.f, 0.f, 0.f};
    const bool lower = (f4 < 32);        // lanes 0..31: i=a half; 32..63: i=t half
    const float* base = &Ps[0][0] + ((f4 & 31) << 2);

    // Wave's s-range of P from LDS (conflict-free: 32 lanes x 16B = full row;
    // upper half-wave duplicates -> broadcast). Shared across all 8 t-planes.
    f32x4 p[16];
#pragma unroll
    for (int k = 0; k < 16; ++k)
        p[k] = *reinterpret_cast<const f32x4*>(base + ((s0 + k) << 7));
    const f32x4 pa = *reinterpret_cast<const f32x4*>(base + (a << 7));
    const float fa = (float)a;

#pragma unroll
    for (int tt = 0; tt < 8; ++tt) {
        const int t = t0 + tt;
        const bool plane_zero = (a == t);            // block-uniform
        const f32x4 ptv = *reinterpret_cast<const f32x4*>(base + (t << 7));
        const f32x4 pi = lower ? pa : ptv;           // per-lane select
        const float fi = lower ? fa : (float)t;
        f32x4* ot = o + tt * 4096;

#pragma unroll
        for (int k = 0; k < 16; ++k) {
            const int s = s0 + k;                    // wave-uniform
            f32x4 v;
            if (plane_zero || s == a || s == t) {    // wave-uniform
                v = z;
            } else {                                  // here s != i for all lanes
                const float r = __builtin_amdgcn_rcpf((float)s - fi);
                v = (p[k] - pi) * r;
            }
            ot[k * 64] = v;
        }
    }
}

extern "C" void kernel_launch(void* const* d_in, const int* in_sizes, int n_in,
                              void* d_out, int out_size, void* d_ws, size_t ws_size,
                              hipStream_t stream) {
    const float* x = (const float*)d_in[0];
    f32x4* out = (f32x4*)d_out;

    writer_kernel<<<B_ * L_ * (L_ / 8), 256, 0, stream>>>(out, x);
}